// Round 10
// baseline (234.736 us; speedup 1.0000x reference)
//
#include <hip/hip_runtime.h>
#include <hip/hip_bf16.h>

// GCN 2-layer forward on MI355X.
// wt+zero -> phase1 (LDS-binned bucket partition) -> bucket_scan ->
// phase2 (per-bucket hist/scan -> rowstart+dinv+csr) ->
// MFMA-GEMM1 (f32 X -> bf16 hs, *dinv) -> agg1 sliced (bf16->bf16, +b1+relu) ->
// MFMA-GEMM2 (bf16 x2 -> bf16 hs, *dinv) -> agg2 sliced (bf16->f32, +b2)
// agg slicing: 32B column slice per block, slice = blockIdx % SLICES pins each
// slice to one XCD (round-robin dispatch) -> hs slice is XCD-L2-resident.

#define IN_C 128
#define HID_C 128
#define OUT_C 64
#define BKT_SH 8
#define BKT_NODES 256
#define CHUNK 4096
#define CAPB 6144
#define OVF_CAP 65536

typedef float f32x4 __attribute__((ext_vector_type(4)));
typedef unsigned u32x4 __attribute__((ext_vector_type(4)));
typedef short bf16x8 __attribute__((ext_vector_type(8)));

__device__ inline unsigned short f2bf_rtn(float f) {
  unsigned u = __float_as_uint(f);
  unsigned r = u + 0x7fffu + ((u >> 16) & 1u);
  return (unsigned short)(r >> 16);
}
__device__ inline unsigned pack_bf2(float a, float b) {
  return (unsigned)f2bf_rtn(a) | ((unsigned)f2bf_rtn(b) << 16);
}

// ---- W transpose + bf16 convert + zero the atomic counters ----
__global__ __launch_bounds__(256) void wt_zero_kernel(
    const float* __restrict__ W1, const float* __restrict__ W2,
    short* __restrict__ w1t, short* __restrict__ w2t,
    int* __restrict__ zbase, int zints) {
  int i = blockIdx.x * 256 + threadIdx.x;
  if (i < zints) zbase[i] = 0;
  if (i < IN_C * HID_C) {
    int n = i >> 7, k = i & 127;
    w1t[i] = (short)f2bf_rtn(W1[k * HID_C + n]);
  }
  if (i < HID_C * OUT_C) {
    int n = i >> 7, k = i & 127;
    w2t[i] = (short)f2bf_rtn(W2[k * OUT_C + n]);
  }
}

// ---- Phase 1: LDS-binned partition -> dense per-bucket runs ----
__global__ __launch_bounds__(256) void phase1_bin_kernel(
    const int* __restrict__ ei, unsigned* __restrict__ pairs,
    int* __restrict__ bcnt, uint2* __restrict__ ovf, int* __restrict__ ovf_cnt,
    int* __restrict__ ovfb, int E, int K) {
  __shared__ unsigned buf[CHUNK];
  __shared__ int hist[256];
  __shared__ int lofs[256];
  __shared__ int cur[256];
  __shared__ int gbase[256];
  int t = threadIdx.x;
  int base_e = blockIdx.x * CHUNK;
  int cnt_e = E - base_e;
  if (cnt_e > CHUNK) cnt_e = CHUNK;

  hist[t] = 0;
  __syncthreads();

  for (int i = t; i < cnt_e; i += 256)
    atomicAdd(&hist[ei[E + base_e + i] >> BKT_SH], 1);
  __syncthreads();

  int v = hist[t];
  int lane = t & 63, wid = t >> 6;
  int inc = v;
  #pragma unroll
  for (int off = 1; off < 64; off <<= 1) {
    int u = __shfl_up(inc, off, 64);
    if (lane >= off) inc += u;
  }
  __shared__ int ws4[4];
  if (lane == 63) ws4[wid] = inc;
  __syncthreads();
  if (t == 0) {
    int a = ws4[0], b = ws4[1], c = ws4[2];
    ws4[0] = 0; ws4[1] = a; ws4[2] = a + b; ws4[3] = a + b + c;
  }
  __syncthreads();
  int excl = ws4[wid] + inc - v;
  lofs[t] = excl;
  cur[t] = excl;
  if (t < K && v > 0) gbase[t] = atomicAdd(&bcnt[t], v);
  __syncthreads();

  for (int i = t; i < cnt_e; i += 256) {
    int src = ei[base_e + i];
    int dst = ei[E + base_e + i];
    int b = dst >> BKT_SH;
    int pos = atomicAdd(&cur[b], 1);
    buf[pos] = (unsigned)src | ((unsigned)(dst & (BKT_NODES - 1)) << 16) |
               ((unsigned)b << 24);
  }
  __syncthreads();

  for (int i = t; i < cnt_e; i += 256) {
    unsigned w = buf[i];
    int b = w >> 24;
    int g = gbase[b] + (i - lofs[b]);
    if (g < CAPB) {
      pairs[(size_t)b * CAPB + g] = w;
    } else {
      int oi = atomicAdd(ovf_cnt, 1);
      if (oi < OVF_CAP) {
        unsigned dst = (unsigned)(b << BKT_SH) | ((w >> 16) & 0xFFu);
        ovf[oi] = make_uint2(w & 0xFFFFu, dst);
        atomicAdd(&ovfb[b], 1);
      }
    }
  }
}

__global__ __launch_bounds__(256) void bucket_scan_kernel(
    const int* __restrict__ bcnt, const int* __restrict__ ovfb,
    int* __restrict__ bucket_base, int* __restrict__ rowstart, int K, int N) {
  int t = threadIdx.x;
  int tot = 0;
  if (t < K) {
    int c = bcnt[t];
    tot = (c < CAPB ? c : CAPB) + ovfb[t];
  }
  int lane = t & 63, wid = t >> 6;
  int inc = tot;
  #pragma unroll
  for (int off = 1; off < 64; off <<= 1) {
    int u = __shfl_up(inc, off, 64);
    if (lane >= off) inc += u;
  }
  __shared__ int ws4[4];
  if (lane == 63) ws4[wid] = inc;
  __syncthreads();
  if (t == 0) {
    int a = ws4[0], b = ws4[1], c = ws4[2];
    ws4[0] = 0; ws4[1] = a; ws4[2] = a + b; ws4[3] = a + b + c;
  }
  __syncthreads();
  int excl = ws4[wid] + inc - tot;
  if (t <= K) bucket_base[t] = excl;
  if (t == K) rowstart[N] = excl;
}

__global__ __launch_bounds__(256) void phase2_csr_kernel(
    const unsigned* __restrict__ pairs, const int* __restrict__ bcnt,
    const uint2* __restrict__ ovf, const int* __restrict__ ovf_cnt,
    const int* __restrict__ bucket_base, int* __restrict__ rowstart,
    float* __restrict__ dinv, unsigned short* __restrict__ csr, int N) {
  int b = blockIdx.x;
  int t = threadIdx.x;
  __shared__ int hist[BKT_NODES];
  __shared__ int cur[BKT_NODES];
  hist[t] = 0;
  __syncthreads();

  int cnt = bcnt[b];
  if (cnt > CAPB) cnt = CAPB;
  const unsigned* reg = pairs + (size_t)b * CAPB;

  for (int i = t; i < cnt; i += 256)
    atomicAdd(&hist[(reg[i] >> 16) & 0xFFu], 1);
  int oc = *ovf_cnt;
  if (oc > OVF_CAP) oc = OVF_CAP;
  for (int i = t; i < oc; i += 256) {
    uint2 p = ovf[i];
    if ((int)(p.y >> BKT_SH) == b) atomicAdd(&hist[p.y & (BKT_NODES - 1)], 1);
  }
  __syncthreads();

  int v = hist[t];
  int lane = t & 63, wid = t >> 6;
  int inc = v;
  #pragma unroll
  for (int off = 1; off < 64; off <<= 1) {
    int u = __shfl_up(inc, off, 64);
    if (lane >= off) inc += u;
  }
  __shared__ int ws4[4];
  if (lane == 63) ws4[wid] = inc;
  __syncthreads();
  if (t == 0) {
    int a = ws4[0], bb = ws4[1], c = ws4[2];
    ws4[0] = 0; ws4[1] = a; ws4[2] = a + bb; ws4[3] = a + bb + c;
  }
  __syncthreads();
  int excl = ws4[wid] + inc - v;

  int base = bucket_base[b];
  int node = b * BKT_NODES + t;
  if (node < N) {
    rowstart[node] = base + excl;
    dinv[node] = rsqrtf((float)(v + 1));
  }
  cur[t] = base + excl;
  __syncthreads();

  for (int i = t; i < cnt; i += 256) {
    unsigned w = reg[i];
    int pos = atomicAdd(&cur[(w >> 16) & 0xFFu], 1);
    csr[pos] = (unsigned short)(w & 0xffffu);
  }
  for (int i = t; i < oc; i += 256) {
    uint2 p = ovf[i];
    if ((int)(p.y >> BKT_SH) == b) {
      int pos = atomicAdd(&cur[p.y & (BKT_NODES - 1)], 1);
      csr[pos] = (unsigned short)p.x;
    }
  }
}

// ---- MFMA GEMM: H[r][c] = bf16( (X[r,:] @ W[:,c]) * dinv[r] ) ----
template <int COUT, bool ABF16>
__global__ __launch_bounds__(256) void mfma_gemm_kernel(
    const void* __restrict__ Xv, const short* __restrict__ Wt,
    const float* __restrict__ dinv, unsigned short* __restrict__ H, int ntiles) {
  int lane = threadIdx.x & 63;
  int tile = blockIdx.x * 4 + (threadIdx.x >> 6);
  if (tile >= ntiles) return;
  constexpr int NT = COUT / 16;

  int arow = tile * 16 + (lane & 15);
  int kch = (lane >> 4) * 8;

  bf16x8 afrag[4];
  if (ABF16) {
    const bf16x8* Xb = (const bf16x8*)Xv;
    #pragma unroll
    for (int kt = 0; kt < 4; ++kt)
      afrag[kt] = Xb[(size_t)arow * 16 + (kt * 32 + kch) / 8];
  } else {
    const float4* Xf = (const float4*)Xv;
    #pragma unroll
    for (int kt = 0; kt < 4; ++kt) {
      float4 f0 = Xf[(size_t)arow * 32 + (kt * 32 + kch) / 4];
      float4 f1 = Xf[(size_t)arow * 32 + (kt * 32 + kch) / 4 + 1];
      bf16x8 a;
      a[0] = (short)f2bf_rtn(f0.x); a[1] = (short)f2bf_rtn(f0.y);
      a[2] = (short)f2bf_rtn(f0.z); a[3] = (short)f2bf_rtn(f0.w);
      a[4] = (short)f2bf_rtn(f1.x); a[5] = (short)f2bf_rtn(f1.y);
      a[6] = (short)f2bf_rtn(f1.z); a[7] = (short)f2bf_rtn(f1.w);
      afrag[kt] = a;
    }
  }

  const bf16x8* W8 = (const bf16x8*)Wt;
  f32x4 zero = {0.f, 0.f, 0.f, 0.f};
  f32x4 acc[NT];
  #pragma unroll
  for (int ct = 0; ct < NT; ++ct) acc[ct] = zero;

  #pragma unroll
  for (int ct = 0; ct < NT; ++ct) {
    int bcol = ct * 16 + (lane & 15);
    #pragma unroll
    for (int kt = 0; kt < 4; ++kt) {
      bf16x8 b = W8[bcol * 16 + (kt * 32 + kch) / 8];
      acc[ct] = __builtin_amdgcn_mfma_f32_16x16x32_bf16(afrag[kt], b, acc[ct], 0, 0, 0);
    }
  }

  int r0 = tile * 16 + (lane >> 4) * 4;
  float di[4];
  #pragma unroll
  for (int j = 0; j < 4; ++j) di[j] = dinv[r0 + j];
  #pragma unroll
  for (int ct = 0; ct < NT; ++ct) {
    #pragma unroll
    for (int j = 0; j < 4; ++j)
      H[(size_t)(r0 + j) * COUT + ct * 16 + (lane & 15)] = f2bf_rtn(acc[ct][j] * di[j]);
  }
}

// ---- sliced pull-agg: each block handles one 32B column slice of 128 nodes.
// slice = blockIdx % SLICES -> same slice lands on same XCD (round-robin
// dispatch), so the hs column slice (N x 64B lines = 3.2MB) stays L2-resident.
template <int C, int SLICES, bool RELU, bool OUT_BF16>
__global__ __launch_bounds__(256) void agg_sliced_kernel(
    const unsigned short* __restrict__ Hs, const int* __restrict__ rowstart,
    const unsigned short* __restrict__ csr, const float* __restrict__ dinv,
    const float* __restrict__ bias, void* __restrict__ out, int n) {
  constexpr int ROW_U4 = C / 8;            // uint4 per row (16 or 8)
  static_assert(ROW_U4 / SLICES == 2, "slice must be 2 uint4 = 32B");
  int slice = blockIdx.x % SLICES;
  int nb = blockIdx.x / SLICES;
  int lane = threadIdx.x & 1;
  int node = nb * 128 + (threadIdx.x >> 1);
  if (node >= n) return;

  const u32x4* H4 = reinterpret_cast<const u32x4*>(Hs);
  int col4 = slice * 2 + lane;             // uint4 index within row
  int s = rowstart[node];
  int e = rowstart[node + 1];

  float acc[8];
  {
    u32x4 v = H4[(size_t)node * ROW_U4 + col4];  // self-loop term
    acc[0] = __uint_as_float(v.x << 16);
    acc[1] = __uint_as_float(v.x & 0xffff0000u);
    acc[2] = __uint_as_float(v.y << 16);
    acc[3] = __uint_as_float(v.y & 0xffff0000u);
    acc[4] = __uint_as_float(v.z << 16);
    acc[5] = __uint_as_float(v.z & 0xffff0000u);
    acc[6] = __uint_as_float(v.w << 16);
    acc[7] = __uint_as_float(v.w & 0xffff0000u);
  }

  int p = s;
  for (; p + 1 < e; p += 2) {
    int s0 = __builtin_nontemporal_load(&csr[p]);
    int s1 = __builtin_nontemporal_load(&csr[p + 1]);
    u32x4 v0 = H4[(size_t)s0 * ROW_U4 + col4];
    u32x4 v1 = H4[(size_t)s1 * ROW_U4 + col4];
    acc[0] += __uint_as_float(v0.x << 16);
    acc[1] += __uint_as_float(v0.x & 0xffff0000u);
    acc[2] += __uint_as_float(v0.y << 16);
    acc[3] += __uint_as_float(v0.y & 0xffff0000u);
    acc[4] += __uint_as_float(v0.z << 16);
    acc[5] += __uint_as_float(v0.z & 0xffff0000u);
    acc[6] += __uint_as_float(v0.w << 16);
    acc[7] += __uint_as_float(v0.w & 0xffff0000u);
    acc[0] += __uint_as_float(v1.x << 16);
    acc[1] += __uint_as_float(v1.x & 0xffff0000u);
    acc[2] += __uint_as_float(v1.y << 16);
    acc[3] += __uint_as_float(v1.y & 0xffff0000u);
    acc[4] += __uint_as_float(v1.z << 16);
    acc[5] += __uint_as_float(v1.z & 0xffff0000u);
    acc[6] += __uint_as_float(v1.w << 16);
    acc[7] += __uint_as_float(v1.w & 0xffff0000u);
  }
  if (p < e) {
    int s0 = __builtin_nontemporal_load(&csr[p]);
    u32x4 v0 = H4[(size_t)s0 * ROW_U4 + col4];
    acc[0] += __uint_as_float(v0.x << 16);
    acc[1] += __uint_as_float(v0.x & 0xffff0000u);
    acc[2] += __uint_as_float(v0.y << 16);
    acc[3] += __uint_as_float(v0.y & 0xffff0000u);
    acc[4] += __uint_as_float(v0.z << 16);
    acc[5] += __uint_as_float(v0.z & 0xffff0000u);
    acc[6] += __uint_as_float(v0.w << 16);
    acc[7] += __uint_as_float(v0.w & 0xffff0000u);
  }

  float di = dinv[node];
  const float4* bias4 = reinterpret_cast<const float4*>(bias);
  float4 b0 = bias4[col4 * 2];
  float4 b1 = bias4[col4 * 2 + 1];
  float r[8];
  r[0] = fmaf(acc[0], di, b0.x);
  r[1] = fmaf(acc[1], di, b0.y);
  r[2] = fmaf(acc[2], di, b0.z);
  r[3] = fmaf(acc[3], di, b0.w);
  r[4] = fmaf(acc[4], di, b1.x);
  r[5] = fmaf(acc[5], di, b1.y);
  r[6] = fmaf(acc[6], di, b1.z);
  r[7] = fmaf(acc[7], di, b1.w);
  if (RELU) {
    #pragma unroll
    for (int j = 0; j < 8; ++j) r[j] = fmaxf(r[j], 0.f);
  }
  if (OUT_BF16) {
    u32x4 o;
    o.x = pack_bf2(r[0], r[1]);
    o.y = pack_bf2(r[2], r[3]);
    o.z = pack_bf2(r[4], r[5]);
    o.w = pack_bf2(r[6], r[7]);
    __builtin_nontemporal_store(o, reinterpret_cast<u32x4*>(out) + (size_t)node * ROW_U4 + col4);
  } else {
    f32x4* o4 = reinterpret_cast<f32x4*>(out) + (size_t)node * (C / 4);
    f32x4 r0v = {r[0], r[1], r[2], r[3]};
    f32x4 r1v = {r[4], r[5], r[6], r[7]};
    __builtin_nontemporal_store(r0v, o4 + col4 * 2);
    __builtin_nontemporal_store(r1v, o4 + col4 * 2 + 1);
  }
}

extern "C" void kernel_launch(void* const* d_in, const int* in_sizes, int n_in,
                              void* d_out, int out_size, void* d_ws, size_t ws_size,
                              hipStream_t stream) {
  const float* x  = (const float*)d_in[0];
  const int*   ei = (const int*)d_in[1];
  const float* W1 = (const float*)d_in[2];
  const float* b1 = (const float*)d_in[3];
  const float* W2 = (const float*)d_in[4];
  const float* b2 = (const float*)d_in[5];
  float* out = (float*)d_out;

  const int N = in_sizes[0] / IN_C;             // 50000
  const int E = in_sizes[1] / 2;                // 800000
  const int K = (N + BKT_NODES - 1) >> BKT_SH;  // 196 buckets
  const int NTILES = (N + 15) / 16;             // 3125
  const int NBLK = (N + 127) / 128;             // 391 node-blocks for agg

  char* ws = (char*)d_ws;
  size_t off = 0;
  auto alloc = [&](size_t bytes) -> void* {
    void* p = ws + off;
    off += (bytes + 255) & ~(size_t)255;
    return p;
  };
  int* bcnt    = (int*)alloc((size_t)K * 4);
  int* ovf_cnt = (int*)alloc(4);
  int* ovfb    = (int*)alloc((size_t)K * 4);
  size_t zero_bytes = off;
  const int zints = (int)(zero_bytes / 4);

  int*   bucket_base = (int*)  alloc((size_t)(K + 1) * 4);
  int*   rowstart    = (int*)  alloc((size_t)(N + 1) * 4);
  float* dinv        = (float*)alloc((size_t)N * 4);
  unsigned* pairs    = (unsigned*)alloc((size_t)K * CAPB * 4);
  uint2* ovf         = (uint2*)alloc((size_t)OVF_CAP * 8);
  unsigned short* csr = (unsigned short*)alloc((size_t)E * 2);
  unsigned short* hs  = (unsigned short*)alloc((size_t)N * HID_C * 2);
  unsigned short* x2  = (unsigned short*)alloc((size_t)N * HID_C * 2);
  short* w1t         = (short*)alloc((size_t)IN_C * HID_C * 2);
  short* w2t         = (short*)alloc((size_t)HID_C * OUT_C * 2);

  int wt_threads = zints > IN_C * HID_C ? zints : IN_C * HID_C;
  wt_zero_kernel<<<(wt_threads + 255) / 256, 256, 0, stream>>>(
      W1, W2, w1t, w2t, (int*)ws, zints);
  phase1_bin_kernel<<<(E + CHUNK - 1) / CHUNK, 256, 0, stream>>>(
      ei, pairs, bcnt, ovf, ovf_cnt, ovfb, E, K);
  bucket_scan_kernel<<<1, 256, 0, stream>>>(bcnt, ovfb, bucket_base, rowstart, K, N);
  phase2_csr_kernel<<<K, 256, 0, stream>>>(
      pairs, bcnt, ovf, ovf_cnt, bucket_base, rowstart, dinv, csr, N);

  mfma_gemm_kernel<HID_C, false><<<(NTILES + 3) / 4, 256, 0, stream>>>(
      x, w1t, dinv, hs, NTILES);
  agg_sliced_kernel<HID_C, 8, true, true><<<8 * NBLK, 256, 0, stream>>>(
      hs, rowstart, csr, dinv, b1, x2, N);

  mfma_gemm_kernel<OUT_C, true><<<(NTILES + 3) / 4, 256, 0, stream>>>(
      x2, w2t, dinv, hs, NTILES);
  agg_sliced_kernel<OUT_C, 4, false, false><<<4 * NBLK, 256, 0, stream>>>(
      hs, rowstart, csr, dinv, b2, out, N);
}

// Round 11
// 110.500 us; speedup vs baseline: 2.1243x; 2.1243x over previous
//
#include <hip/hip_runtime.h>
#include <hip/hip_bf16.h>

// GCN 2-layer forward on MI355X.
// wt+zero -> fat{phase1-bin ∪ MFMA-GEMM1(unscaled)} -> phase2 (inline bucket
// scan -> rowstart+dinv+csr) -> agg1 (dinv[src]-scaled gather, bf16 out) ->
// MFMA-GEMM2 (*dinv, bf16) -> agg2 (pre-scaled, f32 out)

#define IN_C 128
#define HID_C 128
#define OUT_C 64
#define BKT_SH 8
#define BKT_NODES 256
#define CHUNK 4096
#define CAPB 6144
#define OVF_CAP 65536

typedef float f32x4 __attribute__((ext_vector_type(4)));
typedef short bf16x8 __attribute__((ext_vector_type(8)));

__device__ inline unsigned short f2bf_rtn(float f) {
  unsigned u = __float_as_uint(f);
  unsigned r = u + 0x7fffu + ((u >> 16) & 1u);
  return (unsigned short)(r >> 16);
}
__device__ inline unsigned pack_bf2(float a, float b) {
  return (unsigned)f2bf_rtn(a) | ((unsigned)f2bf_rtn(b) << 16);
}

// ---- W transpose + bf16 convert + zero atomic counters ----
__global__ __launch_bounds__(256) void wt_zero_kernel(
    const float* __restrict__ W1, const float* __restrict__ W2,
    short* __restrict__ w1t, short* __restrict__ w2t,
    int* __restrict__ zbase, int zints) {
  int i = blockIdx.x * 256 + threadIdx.x;
  if (i < zints) zbase[i] = 0;
  if (i < IN_C * HID_C) {
    int n = i >> 7, k = i & 127;
    w1t[i] = (short)f2bf_rtn(W1[k * HID_C + n]);
  }
  if (i < HID_C * OUT_C) {
    int n = i >> 7, k = i & 127;
    w2t[i] = (short)f2bf_rtn(W2[k * OUT_C + n]);
  }
}

// ---- Fat kernel: blocks [0,P1B) do LDS-binned edge partition;
//      blocks [P1B, P1B+GB) do MFMA GEMM1 (f32 X @ w1t -> bf16 hs, UNscaled).
__global__ __launch_bounds__(256) void p1_gemm1_kernel(
    const int* __restrict__ ei, unsigned* __restrict__ pairs,
    int* __restrict__ bcnt, uint2* __restrict__ ovf, int* __restrict__ ovf_cnt,
    int* __restrict__ ovfb, int E, int K, int P1B,
    const float* __restrict__ X, const short* __restrict__ Wt,
    unsigned short* __restrict__ H, int ntiles) {
  int t = threadIdx.x;
  if ((int)blockIdx.x < P1B) {
    // ---------- phase1: bucket partition ----------
    __shared__ unsigned buf[CHUNK];
    __shared__ int hist[256];
    __shared__ int lofs[256];
    __shared__ int cur[256];
    __shared__ int gbase[256];
    __shared__ int ws4[4];
    int base_e = blockIdx.x * CHUNK;
    int cnt_e = E - base_e;
    if (cnt_e > CHUNK) cnt_e = CHUNK;

    hist[t] = 0;
    __syncthreads();

    for (int i = t; i < cnt_e; i += 256)
      atomicAdd(&hist[ei[E + base_e + i] >> BKT_SH], 1);
    __syncthreads();

    int v = hist[t];
    int lane = t & 63, wid = t >> 6;
    int inc = v;
    #pragma unroll
    for (int off = 1; off < 64; off <<= 1) {
      int u = __shfl_up(inc, off, 64);
      if (lane >= off) inc += u;
    }
    if (lane == 63) ws4[wid] = inc;
    __syncthreads();
    if (t == 0) {
      int a = ws4[0], b = ws4[1], c = ws4[2];
      ws4[0] = 0; ws4[1] = a; ws4[2] = a + b; ws4[3] = a + b + c;
    }
    __syncthreads();
    int excl = ws4[wid] + inc - v;
    lofs[t] = excl;
    cur[t] = excl;
    if (t < K && v > 0) gbase[t] = atomicAdd(&bcnt[t], v);
    __syncthreads();

    for (int i = t; i < cnt_e; i += 256) {
      int src = ei[base_e + i];
      int dst = ei[E + base_e + i];
      int b = dst >> BKT_SH;
      int pos = atomicAdd(&cur[b], 1);
      buf[pos] = (unsigned)src | ((unsigned)(dst & (BKT_NODES - 1)) << 16) |
                 ((unsigned)b << 24);
    }
    __syncthreads();

    for (int i = t; i < cnt_e; i += 256) {
      unsigned w = buf[i];
      int b = w >> 24;
      int g = gbase[b] + (i - lofs[b]);
      if (g < CAPB) {
        pairs[(size_t)b * CAPB + g] = w;
      } else {
        int oi = atomicAdd(ovf_cnt, 1);
        if (oi < OVF_CAP) {
          unsigned dst = (unsigned)(b << BKT_SH) | ((w >> 16) & 0xFFu);
          ovf[oi] = make_uint2(w & 0xFFFFu, dst);
          atomicAdd(&ovfb[b], 1);
        }
      }
    }
  } else {
    // ---------- GEMM1: one 16-row tile per wave, no dinv scale ----------
    int lane = t & 63;
    int tile = ((int)blockIdx.x - P1B) * 4 + (t >> 6);
    if (tile >= ntiles) return;
    constexpr int NT = HID_C / 16;

    int arow = tile * 16 + (lane & 15);
    int kch = (lane >> 4) * 8;

    bf16x8 afrag[4];
    const float4* Xf = (const float4*)X;
    #pragma unroll
    for (int kt = 0; kt < 4; ++kt) {
      float4 f0 = Xf[(size_t)arow * 32 + (kt * 32 + kch) / 4];
      float4 f1 = Xf[(size_t)arow * 32 + (kt * 32 + kch) / 4 + 1];
      bf16x8 a;
      a[0] = (short)f2bf_rtn(f0.x); a[1] = (short)f2bf_rtn(f0.y);
      a[2] = (short)f2bf_rtn(f0.z); a[3] = (short)f2bf_rtn(f0.w);
      a[4] = (short)f2bf_rtn(f1.x); a[5] = (short)f2bf_rtn(f1.y);
      a[6] = (short)f2bf_rtn(f1.z); a[7] = (short)f2bf_rtn(f1.w);
      afrag[kt] = a;
    }

    const bf16x8* W8 = (const bf16x8*)Wt;
    f32x4 zero = {0.f, 0.f, 0.f, 0.f};
    f32x4 acc[NT];
    #pragma unroll
    for (int ct = 0; ct < NT; ++ct) acc[ct] = zero;

    #pragma unroll
    for (int ct = 0; ct < NT; ++ct) {
      int bcol = ct * 16 + (lane & 15);
      #pragma unroll
      for (int kt = 0; kt < 4; ++kt) {
        bf16x8 b = W8[bcol * 16 + (kt * 32 + kch) / 8];
        acc[ct] = __builtin_amdgcn_mfma_f32_16x16x32_bf16(afrag[kt], b, acc[ct], 0, 0, 0);
      }
    }

    int r0 = tile * 16 + (lane >> 4) * 4;
    #pragma unroll
    for (int ct = 0; ct < NT; ++ct) {
      #pragma unroll
      for (int j = 0; j < 4; ++j)
        H[(size_t)(r0 + j) * HID_C + ct * 16 + (lane & 15)] = f2bf_rtn(acc[ct][j]);
    }
  }
}

// ---- Phase 2: inline bucket-base scan; per-bucket hist/scan ->
//      rowstart + dinv + csr (uint16) ----
__global__ __launch_bounds__(256) void phase2_csr_kernel(
    const unsigned* __restrict__ pairs, const int* __restrict__ bcnt,
    const int* __restrict__ ovfb, const uint2* __restrict__ ovf,
    const int* __restrict__ ovf_cnt, int* __restrict__ rowstart,
    float* __restrict__ dinv, unsigned short* __restrict__ csr, int N, int K) {
  int b = blockIdx.x;
  int t = threadIdx.x;
  __shared__ int hist[BKT_NODES];
  __shared__ int cur[BKT_NODES];
  __shared__ int sbase[256];
  __shared__ int ws4[4];
  int lane = t & 63, wid = t >> 6;

  // inline bucket-base exclusive scan over K buckets
  int cb = 0;
  if (t < K) {
    int c = bcnt[t];
    cb = (c < CAPB ? c : CAPB) + ovfb[t];
  }
  {
    int inc = cb;
    #pragma unroll
    for (int off = 1; off < 64; off <<= 1) {
      int u = __shfl_up(inc, off, 64);
      if (lane >= off) inc += u;
    }
    if (lane == 63) ws4[wid] = inc;
    __syncthreads();
    if (t == 0) {
      int a = ws4[0], bb = ws4[1], c = ws4[2];
      ws4[0] = 0; ws4[1] = a; ws4[2] = a + bb; ws4[3] = a + bb + c;
    }
    __syncthreads();
    int excl = ws4[wid] + inc - cb;
    sbase[t] = excl;
    if (b == K - 1 && t == K - 1) rowstart[N] = excl + cb;  // grand total
  }
  __syncthreads();
  int base = sbase[b];

  hist[t] = 0;
  __syncthreads();

  int cnt = bcnt[b];
  if (cnt > CAPB) cnt = CAPB;
  const unsigned* reg = pairs + (size_t)b * CAPB;

  for (int i = t; i < cnt; i += 256)
    atomicAdd(&hist[(reg[i] >> 16) & 0xFFu], 1);
  int oc = *ovf_cnt;
  if (oc > OVF_CAP) oc = OVF_CAP;
  for (int i = t; i < oc; i += 256) {
    uint2 p = ovf[i];
    if ((int)(p.y >> BKT_SH) == b) atomicAdd(&hist[p.y & (BKT_NODES - 1)], 1);
  }
  __syncthreads();

  int v = hist[t];
  int inc = v;
  #pragma unroll
  for (int off = 1; off < 64; off <<= 1) {
    int u = __shfl_up(inc, off, 64);
    if (lane >= off) inc += u;
  }
  __syncthreads();  // ws4 reuse guard
  if (lane == 63) ws4[wid] = inc;
  __syncthreads();
  if (t == 0) {
    int a = ws4[0], bb = ws4[1], c = ws4[2];
    ws4[0] = 0; ws4[1] = a; ws4[2] = a + bb; ws4[3] = a + bb + c;
  }
  __syncthreads();
  int excl = ws4[wid] + inc - v;

  int node = b * BKT_NODES + t;
  if (node < N) {
    rowstart[node] = base + excl;
    dinv[node] = rsqrtf((float)(v + 1));  // +1 self-loop
  }
  cur[t] = base + excl;
  __syncthreads();

  for (int i = t; i < cnt; i += 256) {
    unsigned w = reg[i];
    int pos = atomicAdd(&cur[(w >> 16) & 0xFFu], 1);
    csr[pos] = (unsigned short)(w & 0xffffu);
  }
  for (int i = t; i < oc; i += 256) {
    uint2 p = ovf[i];
    if ((int)(p.y >> BKT_SH) == b) {
      int pos = atomicAdd(&cur[p.y & (BKT_NODES - 1)], 1);
      csr[pos] = (unsigned short)p.x;
    }
  }
}

// ---- MFMA GEMM (layer 2): H[r][c] = bf16( (X[r,:] @ W[:,c]) * dinv[r] ) ----
__global__ __launch_bounds__(256) void mfma_gemm2_kernel(
    const unsigned short* __restrict__ Xb16, const short* __restrict__ Wt,
    const float* __restrict__ dinv, unsigned short* __restrict__ H, int ntiles) {
  int lane = threadIdx.x & 63;
  int tile = blockIdx.x * 4 + (threadIdx.x >> 6);
  if (tile >= ntiles) return;
  constexpr int NT = OUT_C / 16;

  int arow = tile * 16 + (lane & 15);
  int kch = (lane >> 4) * 8;

  const bf16x8* Xb = (const bf16x8*)Xb16;
  bf16x8 afrag[4];
  #pragma unroll
  for (int kt = 0; kt < 4; ++kt)
    afrag[kt] = Xb[(size_t)arow * 16 + (kt * 32 + kch) / 8];

  const bf16x8* W8 = (const bf16x8*)Wt;
  f32x4 zero = {0.f, 0.f, 0.f, 0.f};
  f32x4 acc[NT];
  #pragma unroll
  for (int ct = 0; ct < NT; ++ct) acc[ct] = zero;

  #pragma unroll
  for (int ct = 0; ct < NT; ++ct) {
    int bcol = ct * 16 + (lane & 15);
    #pragma unroll
    for (int kt = 0; kt < 4; ++kt) {
      bf16x8 b = W8[bcol * 16 + (kt * 32 + kch) / 8];
      acc[ct] = __builtin_amdgcn_mfma_f32_16x16x32_bf16(afrag[kt], b, acc[ct], 0, 0, 0);
    }
  }

  int r0 = tile * 16 + (lane >> 4) * 4;
  float di[4];
  #pragma unroll
  for (int j = 0; j < 4; ++j) di[j] = dinv[r0 + j];
  #pragma unroll
  for (int ct = 0; ct < NT; ++ct) {
    #pragma unroll
    for (int j = 0; j < 4; ++j)
      H[(size_t)(r0 + j) * OUT_C + ct * 16 + (lane & 15)] = f2bf_rtn(acc[ct][j] * di[j]);
  }
}

// ---- pull-agg. SRC_SCALE: messages scaled by dinv[src] at gather time
// (layer 1, hs unscaled); else hs pre-scaled (layer 2). ----
template <int C, bool RELU, bool OUT_BF16, bool SRC_SCALE>
__global__ __launch_bounds__(256) void agg_bf16_kernel(
    const unsigned short* __restrict__ Hs, const int* __restrict__ rowstart,
    const unsigned short* __restrict__ csr, const float* __restrict__ dinv,
    const float* __restrict__ bias, void* __restrict__ out, int n) {
  constexpr int TPN = C / 8;
  constexpr int NPB = 256 / TPN;
  int lane = threadIdx.x % TPN;
  int node = blockIdx.x * NPB + threadIdx.x / TPN;
  if (node >= n) return;

  const uint4* H4 = reinterpret_cast<const uint4*>(Hs);
  int s = rowstart[node];
  int e = rowstart[node + 1];
  float dnode = dinv[node];

  float acc[8];
  {
    uint4 v = H4[(size_t)node * TPN + lane];  // self-loop
    float ds = SRC_SCALE ? dnode : 1.0f;
    acc[0] = __uint_as_float(v.x << 16) * ds;
    acc[1] = __uint_as_float(v.x & 0xffff0000u) * ds;
    acc[2] = __uint_as_float(v.y << 16) * ds;
    acc[3] = __uint_as_float(v.y & 0xffff0000u) * ds;
    acc[4] = __uint_as_float(v.z << 16) * ds;
    acc[5] = __uint_as_float(v.z & 0xffff0000u) * ds;
    acc[6] = __uint_as_float(v.w << 16) * ds;
    acc[7] = __uint_as_float(v.w & 0xffff0000u) * ds;
  }

  int p = s;
  for (; p + 1 < e; p += 2) {
    int s0 = csr[p];
    int s1 = csr[p + 1];
    uint4 v0 = H4[(size_t)s0 * TPN + lane];
    uint4 v1 = H4[(size_t)s1 * TPN + lane];
    if (SRC_SCALE) {
      float d0 = dinv[s0], d1 = dinv[s1];
      acc[0] = fmaf(__uint_as_float(v0.x << 16), d0, acc[0]);
      acc[1] = fmaf(__uint_as_float(v0.x & 0xffff0000u), d0, acc[1]);
      acc[2] = fmaf(__uint_as_float(v0.y << 16), d0, acc[2]);
      acc[3] = fmaf(__uint_as_float(v0.y & 0xffff0000u), d0, acc[3]);
      acc[4] = fmaf(__uint_as_float(v0.z << 16), d0, acc[4]);
      acc[5] = fmaf(__uint_as_float(v0.z & 0xffff0000u), d0, acc[5]);
      acc[6] = fmaf(__uint_as_float(v0.w << 16), d0, acc[6]);
      acc[7] = fmaf(__uint_as_float(v0.w & 0xffff0000u), d0, acc[7]);
      acc[0] = fmaf(__uint_as_float(v1.x << 16), d1, acc[0]);
      acc[1] = fmaf(__uint_as_float(v1.x & 0xffff0000u), d1, acc[1]);
      acc[2] = fmaf(__uint_as_float(v1.y << 16), d1, acc[2]);
      acc[3] = fmaf(__uint_as_float(v1.y & 0xffff0000u), d1, acc[3]);
      acc[4] = fmaf(__uint_as_float(v1.z << 16), d1, acc[4]);
      acc[5] = fmaf(__uint_as_float(v1.z & 0xffff0000u), d1, acc[5]);
      acc[6] = fmaf(__uint_as_float(v1.w << 16), d1, acc[6]);
      acc[7] = fmaf(__uint_as_float(v1.w & 0xffff0000u), d1, acc[7]);
    } else {
      acc[0] += __uint_as_float(v0.x << 16);
      acc[1] += __uint_as_float(v0.x & 0xffff0000u);
      acc[2] += __uint_as_float(v0.y << 16);
      acc[3] += __uint_as_float(v0.y & 0xffff0000u);
      acc[4] += __uint_as_float(v0.z << 16);
      acc[5] += __uint_as_float(v0.z & 0xffff0000u);
      acc[6] += __uint_as_float(v0.w << 16);
      acc[7] += __uint_as_float(v0.w & 0xffff0000u);
      acc[0] += __uint_as_float(v1.x << 16);
      acc[1] += __uint_as_float(v1.x & 0xffff0000u);
      acc[2] += __uint_as_float(v1.y << 16);
      acc[3] += __uint_as_float(v1.y & 0xffff0000u);
      acc[4] += __uint_as_float(v1.z << 16);
      acc[5] += __uint_as_float(v1.z & 0xffff0000u);
      acc[6] += __uint_as_float(v1.w << 16);
      acc[7] += __uint_as_float(v1.w & 0xffff0000u);
    }
  }
  if (p < e) {
    int s0 = csr[p];
    uint4 v0 = H4[(size_t)s0 * TPN + lane];
    float d0 = SRC_SCALE ? dinv[s0] : 1.0f;
    acc[0] = fmaf(__uint_as_float(v0.x << 16), d0, acc[0]);
    acc[1] = fmaf(__uint_as_float(v0.x & 0xffff0000u), d0, acc[1]);
    acc[2] = fmaf(__uint_as_float(v0.y << 16), d0, acc[2]);
    acc[3] = fmaf(__uint_as_float(v0.y & 0xffff0000u), d0, acc[3]);
    acc[4] = fmaf(__uint_as_float(v0.z << 16), d0, acc[4]);
    acc[5] = fmaf(__uint_as_float(v0.z & 0xffff0000u), d0, acc[5]);
    acc[6] = fmaf(__uint_as_float(v0.w << 16), d0, acc[6]);
    acc[7] = fmaf(__uint_as_float(v0.w & 0xffff0000u), d0, acc[7]);
  }

  float4 b0 = reinterpret_cast<const float4*>(bias)[lane * 2];
  float4 b1 = reinterpret_cast<const float4*>(bias)[lane * 2 + 1];
  float r[8];
  r[0] = fmaf(acc[0], dnode, b0.x);
  r[1] = fmaf(acc[1], dnode, b0.y);
  r[2] = fmaf(acc[2], dnode, b0.z);
  r[3] = fmaf(acc[3], dnode, b0.w);
  r[4] = fmaf(acc[4], dnode, b1.x);
  r[5] = fmaf(acc[5], dnode, b1.y);
  r[6] = fmaf(acc[6], dnode, b1.z);
  r[7] = fmaf(acc[7], dnode, b1.w);
  if (RELU) {
    #pragma unroll
    for (int j = 0; j < 8; ++j) r[j] = fmaxf(r[j], 0.f);
  }
  if (OUT_BF16) {
    uint4 o;
    o.x = pack_bf2(r[0], r[1]);
    o.y = pack_bf2(r[2], r[3]);
    o.z = pack_bf2(r[4], r[5]);
    o.w = pack_bf2(r[6], r[7]);
    reinterpret_cast<uint4*>(out)[(size_t)node * TPN + lane] = o;
  } else {
    float4* o4 = reinterpret_cast<float4*>(out) + (size_t)node * (C / 4);
    o4[lane * 2] = make_float4(r[0], r[1], r[2], r[3]);
    o4[lane * 2 + 1] = make_float4(r[4], r[5], r[6], r[7]);
  }
}

extern "C" void kernel_launch(void* const* d_in, const int* in_sizes, int n_in,
                              void* d_out, int out_size, void* d_ws, size_t ws_size,
                              hipStream_t stream) {
  const float* x  = (const float*)d_in[0];
  const int*   ei = (const int*)d_in[1];
  const float* W1 = (const float*)d_in[2];
  const float* b1 = (const float*)d_in[3];
  const float* W2 = (const float*)d_in[4];
  const float* b2 = (const float*)d_in[5];
  float* out = (float*)d_out;

  const int N = in_sizes[0] / IN_C;             // 50000
  const int E = in_sizes[1] / 2;                // 800000
  const int K = (N + BKT_NODES - 1) >> BKT_SH;  // 196 buckets
  const int NTILES = (N + 15) / 16;             // 3125
  const int P1B = (E + CHUNK - 1) / CHUNK;      // 196 phase1 blocks
  const int GB1 = (NTILES + 3) / 4;             // 782 gemm1 blocks

  char* ws = (char*)d_ws;
  size_t off = 0;
  auto alloc = [&](size_t bytes) -> void* {
    void* p = ws + off;
    off += (bytes + 255) & ~(size_t)255;
    return p;
  };
  int* bcnt    = (int*)alloc((size_t)K * 4);
  int* ovf_cnt = (int*)alloc(4);
  int* ovfb    = (int*)alloc((size_t)K * 4);
  size_t zero_bytes = off;
  const int zints = (int)(zero_bytes / 4);

  int*   rowstart    = (int*)  alloc((size_t)(N + 1) * 4);
  float* dinv        = (float*)alloc((size_t)N * 4);
  unsigned* pairs    = (unsigned*)alloc((size_t)K * CAPB * 4);
  uint2* ovf         = (uint2*)alloc((size_t)OVF_CAP * 8);
  unsigned short* csr = (unsigned short*)alloc((size_t)E * 2);
  unsigned short* hs  = (unsigned short*)alloc((size_t)N * HID_C * 2);
  unsigned short* x2  = (unsigned short*)alloc((size_t)N * HID_C * 2);
  short* w1t         = (short*)alloc((size_t)IN_C * HID_C * 2);
  short* w2t         = (short*)alloc((size_t)HID_C * OUT_C * 2);

  int wt_threads = zints > IN_C * HID_C ? zints : IN_C * HID_C;
  wt_zero_kernel<<<(wt_threads + 255) / 256, 256, 0, stream>>>(
      W1, W2, w1t, w2t, (int*)ws, zints);

  p1_gemm1_kernel<<<P1B + GB1, 256, 0, stream>>>(
      ei, pairs, bcnt, ovf, ovf_cnt, ovfb, E, K, P1B, x, w1t, hs, NTILES);

  phase2_csr_kernel<<<K, 256, 0, stream>>>(
      pairs, bcnt, ovfb, ovf, ovf_cnt, rowstart, dinv, csr, N, K);

  agg_bf16_kernel<HID_C, true, true, true><<<(N + 15) / 16, 256, 0, stream>>>(
      hs, rowstart, csr, dinv, b1, x2, N);

  mfma_gemm2_kernel<<<(NTILES + 3) / 4, 256, 0, stream>>>(
      x2, w2t, dinv, hs, NTILES);

  agg_bf16_kernel<OUT_C, false, false, false><<<(N + 31) / 32, 256, 0, stream>>>(
      hs, rowstart, csr, dinv, b2, out, N);
}

// Round 12
// 102.919 us; speedup vs baseline: 2.2808x; 1.0737x over previous
//
#include <hip/hip_runtime.h>
#include <hip/hip_bf16.h>

// GCN 2-layer forward on MI355X.
// wt+zero -> fat{phase1-bin ∪ MFMA-GEMM1(unscaled)} -> phase2 (inline bucket
// scan -> rowstart+dinv+csr) -> FUSED agg1(dinv[src]-scaled)+relu+GEMM2(*dinv)
// -> agg2 (pre-scaled, f32 out)

#define IN_C 128
#define HID_C 128
#define OUT_C 64
#define BKT_SH 8
#define BKT_NODES 256
#define CHUNK 4096
#define CAPB 6144
#define OVF_CAP 65536

typedef float f32x4 __attribute__((ext_vector_type(4)));
typedef short bf16x8 __attribute__((ext_vector_type(8)));

__device__ inline unsigned short f2bf_rtn(float f) {
  unsigned u = __float_as_uint(f);
  unsigned r = u + 0x7fffu + ((u >> 16) & 1u);
  return (unsigned short)(r >> 16);
}
__device__ inline unsigned pack_bf2(float a, float b) {
  return (unsigned)f2bf_rtn(a) | ((unsigned)f2bf_rtn(b) << 16);
}

// ---- W transpose + bf16 convert + zero atomic counters ----
__global__ __launch_bounds__(256) void wt_zero_kernel(
    const float* __restrict__ W1, const float* __restrict__ W2,
    short* __restrict__ w1t, short* __restrict__ w2t,
    int* __restrict__ zbase, int zints) {
  int i = blockIdx.x * 256 + threadIdx.x;
  if (i < zints) zbase[i] = 0;
  if (i < IN_C * HID_C) {
    int n = i >> 7, k = i & 127;
    w1t[i] = (short)f2bf_rtn(W1[k * HID_C + n]);
  }
  if (i < HID_C * OUT_C) {
    int n = i >> 7, k = i & 127;
    w2t[i] = (short)f2bf_rtn(W2[k * OUT_C + n]);
  }
}

// ---- Fat kernel: blocks [0,P1B) = LDS-binned edge partition;
//      blocks [P1B, P1B+GB) = MFMA GEMM1 (f32 X @ w1t -> bf16 hs, UNscaled).
__global__ __launch_bounds__(256) void p1_gemm1_kernel(
    const int* __restrict__ ei, unsigned* __restrict__ pairs,
    int* __restrict__ bcnt, uint2* __restrict__ ovf, int* __restrict__ ovf_cnt,
    int* __restrict__ ovfb, int E, int K, int P1B,
    const float* __restrict__ X, const short* __restrict__ Wt,
    unsigned short* __restrict__ H, int ntiles) {
  int t = threadIdx.x;
  if ((int)blockIdx.x < P1B) {
    __shared__ unsigned buf[CHUNK];
    __shared__ int hist[256];
    __shared__ int lofs[256];
    __shared__ int cur[256];
    __shared__ int gbase[256];
    __shared__ int ws4[4];
    int base_e = blockIdx.x * CHUNK;
    int cnt_e = E - base_e;
    if (cnt_e > CHUNK) cnt_e = CHUNK;

    hist[t] = 0;
    __syncthreads();

    for (int i = t; i < cnt_e; i += 256)
      atomicAdd(&hist[ei[E + base_e + i] >> BKT_SH], 1);
    __syncthreads();

    int v = hist[t];
    int lane = t & 63, wid = t >> 6;
    int inc = v;
    #pragma unroll
    for (int off = 1; off < 64; off <<= 1) {
      int u = __shfl_up(inc, off, 64);
      if (lane >= off) inc += u;
    }
    if (lane == 63) ws4[wid] = inc;
    __syncthreads();
    if (t == 0) {
      int a = ws4[0], b = ws4[1], c = ws4[2];
      ws4[0] = 0; ws4[1] = a; ws4[2] = a + b; ws4[3] = a + b + c;
    }
    __syncthreads();
    int excl = ws4[wid] + inc - v;
    lofs[t] = excl;
    cur[t] = excl;
    if (t < K && v > 0) gbase[t] = atomicAdd(&bcnt[t], v);
    __syncthreads();

    for (int i = t; i < cnt_e; i += 256) {
      int src = ei[base_e + i];
      int dst = ei[E + base_e + i];
      int b = dst >> BKT_SH;
      int pos = atomicAdd(&cur[b], 1);
      buf[pos] = (unsigned)src | ((unsigned)(dst & (BKT_NODES - 1)) << 16) |
                 ((unsigned)b << 24);
    }
    __syncthreads();

    for (int i = t; i < cnt_e; i += 256) {
      unsigned w = buf[i];
      int b = w >> 24;
      int g = gbase[b] + (i - lofs[b]);
      if (g < CAPB) {
        pairs[(size_t)b * CAPB + g] = w;
      } else {
        int oi = atomicAdd(ovf_cnt, 1);
        if (oi < OVF_CAP) {
          unsigned dst = (unsigned)(b << BKT_SH) | ((w >> 16) & 0xFFu);
          ovf[oi] = make_uint2(w & 0xFFFFu, dst);
          atomicAdd(&ovfb[b], 1);
        }
      }
    }
  } else {
    // ---------- GEMM1: one 16-row tile per wave, no dinv scale ----------
    int lane = t & 63;
    int tile = ((int)blockIdx.x - P1B) * 4 + (t >> 6);
    if (tile >= ntiles) return;
    constexpr int NT = HID_C / 16;

    int arow = tile * 16 + (lane & 15);
    int kch = (lane >> 4) * 8;

    bf16x8 afrag[4];
    const float4* Xf = (const float4*)X;
    #pragma unroll
    for (int kt = 0; kt < 4; ++kt) {
      float4 f0 = Xf[(size_t)arow * 32 + (kt * 32 + kch) / 4];
      float4 f1 = Xf[(size_t)arow * 32 + (kt * 32 + kch) / 4 + 1];
      bf16x8 a;
      a[0] = (short)f2bf_rtn(f0.x); a[1] = (short)f2bf_rtn(f0.y);
      a[2] = (short)f2bf_rtn(f0.z); a[3] = (short)f2bf_rtn(f0.w);
      a[4] = (short)f2bf_rtn(f1.x); a[5] = (short)f2bf_rtn(f1.y);
      a[6] = (short)f2bf_rtn(f1.z); a[7] = (short)f2bf_rtn(f1.w);
      afrag[kt] = a;
    }

    const bf16x8* W8 = (const bf16x8*)Wt;
    f32x4 zero = {0.f, 0.f, 0.f, 0.f};
    f32x4 acc[NT];
    #pragma unroll
    for (int ct = 0; ct < NT; ++ct) acc[ct] = zero;

    #pragma unroll
    for (int ct = 0; ct < NT; ++ct) {
      int bcol = ct * 16 + (lane & 15);
      #pragma unroll
      for (int kt = 0; kt < 4; ++kt) {
        bf16x8 b = W8[bcol * 16 + (kt * 32 + kch) / 8];
        acc[ct] = __builtin_amdgcn_mfma_f32_16x16x32_bf16(afrag[kt], b, acc[ct], 0, 0, 0);
      }
    }

    int r0 = tile * 16 + (lane >> 4) * 4;
    #pragma unroll
    for (int ct = 0; ct < NT; ++ct) {
      #pragma unroll
      for (int j = 0; j < 4; ++j)
        H[(size_t)(r0 + j) * HID_C + ct * 16 + (lane & 15)] = f2bf_rtn(acc[ct][j]);
    }
  }
}

// ---- Phase 2: inline bucket-base scan; per-bucket hist/scan ->
//      rowstart + dinv + csr (uint16) ----
__global__ __launch_bounds__(256) void phase2_csr_kernel(
    const unsigned* __restrict__ pairs, const int* __restrict__ bcnt,
    const int* __restrict__ ovfb, const uint2* __restrict__ ovf,
    const int* __restrict__ ovf_cnt, int* __restrict__ rowstart,
    float* __restrict__ dinv, unsigned short* __restrict__ csr, int N, int K) {
  int b = blockIdx.x;
  int t = threadIdx.x;
  __shared__ int hist[BKT_NODES];
  __shared__ int cur[BKT_NODES];
  __shared__ int sbase[256];
  __shared__ int ws4[4];
  int lane = t & 63, wid = t >> 6;

  int cb = 0;
  if (t < K) {
    int c = bcnt[t];
    cb = (c < CAPB ? c : CAPB) + ovfb[t];
  }
  {
    int inc = cb;
    #pragma unroll
    for (int off = 1; off < 64; off <<= 1) {
      int u = __shfl_up(inc, off, 64);
      if (lane >= off) inc += u;
    }
    if (lane == 63) ws4[wid] = inc;
    __syncthreads();
    if (t == 0) {
      int a = ws4[0], bb = ws4[1], c = ws4[2];
      ws4[0] = 0; ws4[1] = a; ws4[2] = a + bb; ws4[3] = a + bb + c;
    }
    __syncthreads();
    int excl = ws4[wid] + inc - cb;
    sbase[t] = excl;
    if (b == K - 1 && t == K - 1) rowstart[N] = excl + cb;
  }
  __syncthreads();
  int base = sbase[b];

  hist[t] = 0;
  __syncthreads();

  int cnt = bcnt[b];
  if (cnt > CAPB) cnt = CAPB;
  const unsigned* reg = pairs + (size_t)b * CAPB;

  for (int i = t; i < cnt; i += 256)
    atomicAdd(&hist[(reg[i] >> 16) & 0xFFu], 1);
  int oc = *ovf_cnt;
  if (oc > OVF_CAP) oc = OVF_CAP;
  for (int i = t; i < oc; i += 256) {
    uint2 p = ovf[i];
    if ((int)(p.y >> BKT_SH) == b) atomicAdd(&hist[p.y & (BKT_NODES - 1)], 1);
  }
  __syncthreads();

  int v = hist[t];
  int inc = v;
  #pragma unroll
  for (int off = 1; off < 64; off <<= 1) {
    int u = __shfl_up(inc, off, 64);
    if (lane >= off) inc += u;
  }
  __syncthreads();
  if (lane == 63) ws4[wid] = inc;
  __syncthreads();
  if (t == 0) {
    int a = ws4[0], bb = ws4[1], c = ws4[2];
    ws4[0] = 0; ws4[1] = a; ws4[2] = a + bb; ws4[3] = a + bb + c;
  }
  __syncthreads();
  int excl = ws4[wid] + inc - v;

  int node = b * BKT_NODES + t;
  if (node < N) {
    rowstart[node] = base + excl;
    dinv[node] = rsqrtf((float)(v + 1));
  }
  cur[t] = base + excl;
  __syncthreads();

  for (int i = t; i < cnt; i += 256) {
    unsigned w = reg[i];
    int pos = atomicAdd(&cur[(w >> 16) & 0xFFu], 1);
    csr[pos] = (unsigned short)(w & 0xffffu);
  }
  for (int i = t; i < oc; i += 256) {
    uint2 p = ovf[i];
    if ((int)(p.y >> BKT_SH) == b) {
      int pos = atomicAdd(&cur[p.y & (BKT_NODES - 1)], 1);
      csr[pos] = (unsigned short)p.x;
    }
  }
}

// ---- FUSED: agg1 (dinv[src]-scaled gather over hs, +b1, relu) -> LDS tile
//      -> MFMA GEMM2 (x2tile @ w2t) * dinv[row] -> hs2 (bf16).
// Block = 256 threads = 16 nodes x 16 lanes. x2 never touches global.
__global__ __launch_bounds__(256) void agg1_gemm2_kernel(
    const unsigned short* __restrict__ Hs, const int* __restrict__ rowstart,
    const unsigned short* __restrict__ csr, const float* __restrict__ dinv,
    const float* __restrict__ b1, const short* __restrict__ w2t,
    unsigned short* __restrict__ H2, int n) {
  __shared__ unsigned x2s[16][64];  // 16 rows x 128 bf16 (as 64 u32) = 4KB
  int t = threadIdx.x;
  int row = t >> 4;          // 0..15
  int lane16 = t & 15;       // channel group
  int node = blockIdx.x * 16 + row;

  float acc[8];
  #pragma unroll
  for (int j = 0; j < 8; ++j) acc[j] = 0.f;

  if (node < n) {
    const uint4* H4 = reinterpret_cast<const uint4*>(Hs);
    int s = rowstart[node];
    int e = rowstart[node + 1];
    float dnode = dinv[node];

    {
      uint4 v = H4[(size_t)node * 16 + lane16];  // self-loop
      acc[0] = __uint_as_float(v.x << 16) * dnode;
      acc[1] = __uint_as_float(v.x & 0xffff0000u) * dnode;
      acc[2] = __uint_as_float(v.y << 16) * dnode;
      acc[3] = __uint_as_float(v.y & 0xffff0000u) * dnode;
      acc[4] = __uint_as_float(v.z << 16) * dnode;
      acc[5] = __uint_as_float(v.z & 0xffff0000u) * dnode;
      acc[6] = __uint_as_float(v.w << 16) * dnode;
      acc[7] = __uint_as_float(v.w & 0xffff0000u) * dnode;
    }

    int p = s;
    for (; p + 1 < e; p += 2) {
      int s0 = csr[p];
      int s1 = csr[p + 1];
      uint4 v0 = H4[(size_t)s0 * 16 + lane16];
      uint4 v1 = H4[(size_t)s1 * 16 + lane16];
      float d0 = dinv[s0], d1 = dinv[s1];
      acc[0] = fmaf(__uint_as_float(v0.x << 16), d0, acc[0]);
      acc[1] = fmaf(__uint_as_float(v0.x & 0xffff0000u), d0, acc[1]);
      acc[2] = fmaf(__uint_as_float(v0.y << 16), d0, acc[2]);
      acc[3] = fmaf(__uint_as_float(v0.y & 0xffff0000u), d0, acc[3]);
      acc[4] = fmaf(__uint_as_float(v0.z << 16), d0, acc[4]);
      acc[5] = fmaf(__uint_as_float(v0.z & 0xffff0000u), d0, acc[5]);
      acc[6] = fmaf(__uint_as_float(v0.w << 16), d0, acc[6]);
      acc[7] = fmaf(__uint_as_float(v0.w & 0xffff0000u), d0, acc[7]);
      acc[0] = fmaf(__uint_as_float(v1.x << 16), d1, acc[0]);
      acc[1] = fmaf(__uint_as_float(v1.x & 0xffff0000u), d1, acc[1]);
      acc[2] = fmaf(__uint_as_float(v1.y << 16), d1, acc[2]);
      acc[3] = fmaf(__uint_as_float(v1.y & 0xffff0000u), d1, acc[3]);
      acc[4] = fmaf(__uint_as_float(v1.z << 16), d1, acc[4]);
      acc[5] = fmaf(__uint_as_float(v1.z & 0xffff0000u), d1, acc[5]);
      acc[6] = fmaf(__uint_as_float(v1.w << 16), d1, acc[6]);
      acc[7] = fmaf(__uint_as_float(v1.w & 0xffff0000u), d1, acc[7]);
    }
    if (p < e) {
      int s0 = csr[p];
      uint4 v0 = H4[(size_t)s0 * 16 + lane16];
      float d0 = dinv[s0];
      acc[0] = fmaf(__uint_as_float(v0.x << 16), d0, acc[0]);
      acc[1] = fmaf(__uint_as_float(v0.x & 0xffff0000u), d0, acc[1]);
      acc[2] = fmaf(__uint_as_float(v0.y << 16), d0, acc[2]);
      acc[3] = fmaf(__uint_as_float(v0.y & 0xffff0000u), d0, acc[3]);
      acc[4] = fmaf(__uint_as_float(v0.z << 16), d0, acc[4]);
      acc[5] = fmaf(__uint_as_float(v0.z & 0xffff0000u), d0, acc[5]);
      acc[6] = fmaf(__uint_as_float(v0.w << 16), d0, acc[6]);
      acc[7] = fmaf(__uint_as_float(v0.w & 0xffff0000u), d0, acc[7]);
    }

    const float4* b4 = reinterpret_cast<const float4*>(b1);
    float4 bv0 = b4[lane16 * 2];
    float4 bv1 = b4[lane16 * 2 + 1];
    acc[0] = fmaxf(fmaf(acc[0], dnode, bv0.x), 0.f);
    acc[1] = fmaxf(fmaf(acc[1], dnode, bv0.y), 0.f);
    acc[2] = fmaxf(fmaf(acc[2], dnode, bv0.z), 0.f);
    acc[3] = fmaxf(fmaf(acc[3], dnode, bv0.w), 0.f);
    acc[4] = fmaxf(fmaf(acc[4], dnode, bv1.x), 0.f);
    acc[5] = fmaxf(fmaf(acc[5], dnode, bv1.y), 0.f);
    acc[6] = fmaxf(fmaf(acc[6], dnode, bv1.z), 0.f);
    acc[7] = fmaxf(fmaf(acc[7], dnode, bv1.w), 0.f);
  }

  // pack x2 row to LDS (bf16)
  x2s[row][lane16 * 4 + 0] = pack_bf2(acc[0], acc[1]);
  x2s[row][lane16 * 4 + 1] = pack_bf2(acc[2], acc[3]);
  x2s[row][lane16 * 4 + 2] = pack_bf2(acc[4], acc[5]);
  x2s[row][lane16 * 4 + 3] = pack_bf2(acc[6], acc[7]);
  __syncthreads();

  // GEMM2: wave w computes 16-col slice ct=w of the 16x64 output tile.
  int lane = t & 63;
  int w = t >> 6;
  int kch = (lane >> 4) * 8;   // bf16 offset within 32-k chunk

  const bf16x8* W8 = (const bf16x8*)w2t;
  f32x4 oacc = {0.f, 0.f, 0.f, 0.f};
  int bcol = w * 16 + (lane & 15);
  #pragma unroll
  for (int kt = 0; kt < 4; ++kt) {
    // A-frag: row = lane&15, k = kt*32 + kch .. +8  -> u32 offset kt*16 + kch/2
    bf16x8 a = *reinterpret_cast<const bf16x8*>(&x2s[lane & 15][kt * 16 + kch / 2]);
    bf16x8 b = W8[bcol * 16 + (kt * 32 + kch) / 8];
    oacc = __builtin_amdgcn_mfma_f32_16x16x32_bf16(a, b, oacc, 0, 0, 0);
  }

  int r0 = (lane >> 4) * 4;
  #pragma unroll
  for (int j = 0; j < 4; ++j) {
    int g = blockIdx.x * 16 + r0 + j;
    if (g < n)
      H2[(size_t)g * OUT_C + w * 16 + (lane & 15)] = f2bf_rtn(oacc[j] * dinv[g]);
  }
}

// ---- agg2: out[node,:] = dinv[node]*(hs2[node,:]+sum hs2[src,:]) + b2 ----
__global__ __launch_bounds__(256) void agg2_kernel(
    const unsigned short* __restrict__ Hs, const int* __restrict__ rowstart,
    const unsigned short* __restrict__ csr, const float* __restrict__ dinv,
    const float* __restrict__ bias, float* __restrict__ out, int n) {
  constexpr int TPN = OUT_C / 8;   // 8
  constexpr int NPB = 256 / TPN;   // 32
  int lane = threadIdx.x % TPN;
  int node = blockIdx.x * NPB + threadIdx.x / TPN;
  if (node >= n) return;

  const uint4* H4 = reinterpret_cast<const uint4*>(Hs);
  int s = rowstart[node];
  int e = rowstart[node + 1];

  float acc[8];
  {
    uint4 v = H4[(size_t)node * TPN + lane];
    acc[0] = __uint_as_float(v.x << 16);
    acc[1] = __uint_as_float(v.x & 0xffff0000u);
    acc[2] = __uint_as_float(v.y << 16);
    acc[3] = __uint_as_float(v.y & 0xffff0000u);
    acc[4] = __uint_as_float(v.z << 16);
    acc[5] = __uint_as_float(v.z & 0xffff0000u);
    acc[6] = __uint_as_float(v.w << 16);
    acc[7] = __uint_as_float(v.w & 0xffff0000u);
  }

  int p = s;
  for (; p + 1 < e; p += 2) {
    int s0 = csr[p];
    int s1 = csr[p + 1];
    uint4 v0 = H4[(size_t)s0 * TPN + lane];
    uint4 v1 = H4[(size_t)s1 * TPN + lane];
    acc[0] += __uint_as_float(v0.x << 16);
    acc[1] += __uint_as_float(v0.x & 0xffff0000u);
    acc[2] += __uint_as_float(v0.y << 16);
    acc[3] += __uint_as_float(v0.y & 0xffff0000u);
    acc[4] += __uint_as_float(v0.z << 16);
    acc[5] += __uint_as_float(v0.z & 0xffff0000u);
    acc[6] += __uint_as_float(v0.w << 16);
    acc[7] += __uint_as_float(v0.w & 0xffff0000u);
    acc[0] += __uint_as_float(v1.x << 16);
    acc[1] += __uint_as_float(v1.x & 0xffff0000u);
    acc[2] += __uint_as_float(v1.y << 16);
    acc[3] += __uint_as_float(v1.y & 0xffff0000u);
    acc[4] += __uint_as_float(v1.z << 16);
    acc[5] += __uint_as_float(v1.z & 0xffff0000u);
    acc[6] += __uint_as_float(v1.w << 16);
    acc[7] += __uint_as_float(v1.w & 0xffff0000u);
  }
  if (p < e) {
    int s0 = csr[p];
    uint4 v0 = H4[(size_t)s0 * TPN + lane];
    acc[0] += __uint_as_float(v0.x << 16);
    acc[1] += __uint_as_float(v0.x & 0xffff0000u);
    acc[2] += __uint_as_float(v0.y << 16);
    acc[3] += __uint_as_float(v0.y & 0xffff0000u);
    acc[4] += __uint_as_float(v0.z << 16);
    acc[5] += __uint_as_float(v0.z & 0xffff0000u);
    acc[6] += __uint_as_float(v0.w << 16);
    acc[7] += __uint_as_float(v0.w & 0xffff0000u);
  }

  float dnode = dinv[node];
  float4 b0 = reinterpret_cast<const float4*>(bias)[lane * 2];
  float4 b1 = reinterpret_cast<const float4*>(bias)[lane * 2 + 1];
  float4* o4 = reinterpret_cast<float4*>(out) + (size_t)node * (OUT_C / 4);
  o4[lane * 2] = make_float4(fmaf(acc[0], dnode, b0.x), fmaf(acc[1], dnode, b0.y),
                             fmaf(acc[2], dnode, b0.z), fmaf(acc[3], dnode, b0.w));
  o4[lane * 2 + 1] = make_float4(fmaf(acc[4], dnode, b1.x), fmaf(acc[5], dnode, b1.y),
                                 fmaf(acc[6], dnode, b1.z), fmaf(acc[7], dnode, b1.w));
}

extern "C" void kernel_launch(void* const* d_in, const int* in_sizes, int n_in,
                              void* d_out, int out_size, void* d_ws, size_t ws_size,
                              hipStream_t stream) {
  const float* x  = (const float*)d_in[0];
  const int*   ei = (const int*)d_in[1];
  const float* W1 = (const float*)d_in[2];
  const float* b1 = (const float*)d_in[3];
  const float* W2 = (const float*)d_in[4];
  const float* b2 = (const float*)d_in[5];
  float* out = (float*)d_out;

  const int N = in_sizes[0] / IN_C;             // 50000
  const int E = in_sizes[1] / 2;                // 800000
  const int K = (N + BKT_NODES - 1) >> BKT_SH;  // 196 buckets
  const int NTILES = (N + 15) / 16;             // 3125
  const int P1B = (E + CHUNK - 1) / CHUNK;      // 196
  const int GB1 = (NTILES + 3) / 4;             // 782

  char* ws = (char*)d_ws;
  size_t off = 0;
  auto alloc = [&](size_t bytes) -> void* {
    void* p = ws + off;
    off += (bytes + 255) & ~(size_t)255;
    return p;
  };
  int* bcnt    = (int*)alloc((size_t)K * 4);
  int* ovf_cnt = (int*)alloc(4);
  int* ovfb    = (int*)alloc((size_t)K * 4);
  size_t zero_bytes = off;
  const int zints = (int)(zero_bytes / 4);

  int*   rowstart    = (int*)  alloc((size_t)(N + 1) * 4);
  float* dinv        = (float*)alloc((size_t)N * 4);
  unsigned* pairs    = (unsigned*)alloc((size_t)K * CAPB * 4);
  uint2* ovf         = (uint2*)alloc((size_t)OVF_CAP * 8);
  unsigned short* csr = (unsigned short*)alloc((size_t)E * 2);
  unsigned short* hs  = (unsigned short*)alloc((size_t)N * HID_C * 2);
  unsigned short* hs2 = (unsigned short*)alloc((size_t)N * OUT_C * 2);
  short* w1t         = (short*)alloc((size_t)IN_C * HID_C * 2);
  short* w2t         = (short*)alloc((size_t)HID_C * OUT_C * 2);

  int wt_threads = zints > IN_C * HID_C ? zints : IN_C * HID_C;
  wt_zero_kernel<<<(wt_threads + 255) / 256, 256, 0, stream>>>(
      W1, W2, w1t, w2t, (int*)ws, zints);

  p1_gemm1_kernel<<<P1B + GB1, 256, 0, stream>>>(
      ei, pairs, bcnt, ovf, ovf_cnt, ovfb, E, K, P1B, x, w1t, hs, NTILES);

  phase2_csr_kernel<<<K, 256, 0, stream>>>(
      pairs, bcnt, ovfb, ovf, ovf_cnt, rowstart, dinv, csr, N, K);

  agg1_gemm2_kernel<<<NTILES, 256, 0, stream>>>(
      hs, rowstart, csr, dinv, b1, w2t, hs2, N);

  agg2_kernel<<<(N + 31) / 32, 256, 0, stream>>>(
      hs2, rowstart, csr, dinv, b2, out, N);
}